// Round 2
// baseline (351.557 us; speedup 1.0000x reference)
//
#include <hip/hip_runtime.h>

#define DIM 64
#define BN_EPS 1e-5f
#define L2_EPS 1e-12f

__global__ __launch_bounds__(256) void k_init_deg(float* __restrict__ deg, int N) {
    int i = blockIdx.x * blockDim.x + threadIdx.x;
    if (i < N) deg[i] = 1.0f;
}

__global__ __launch_bounds__(256) void k_count_deg(const int* __restrict__ ei,
                                                   float* __restrict__ deg, int E) {
    int e = blockIdx.x * blockDim.x + threadIdx.x;
    if (e < E) atomicAdd(&deg[ei[E + e]], 1.0f);
}

__global__ __launch_bounds__(256) void k_rsqrt_deg(float* __restrict__ deg, int N) {
    int i = blockIdx.x * blockDim.x + threadIdx.x;
    if (i < N) deg[i] = rsqrtf(deg[i]);   // in-place: deg -> dinv
}

// h = x @ W ; out = h * dinv^2 + b   (self-loop term + bias folded in)
__global__ __launch_bounds__(256) void k_gemm(const float* __restrict__ x,
                                              const float* __restrict__ W,
                                              const float* __restrict__ b,
                                              const float* __restrict__ dinv,
                                              float* __restrict__ h,
                                              float* __restrict__ out, int N) {
    __shared__ float Ws[DIM][DIM];   // 16 KiB
    __shared__ float xs[4][DIM];
    int tid = threadIdx.x;
    for (int i = tid; i < DIM * DIM; i += 256) Ws[i >> 6][i & 63] = W[i];
    __syncthreads();
    int tx = tid & 63, ty = tid >> 6;
    float bj = b[tx];
    for (int r0 = blockIdx.x * 4; r0 < N; r0 += gridDim.x * 4) {
        int r = r0 + ty;           // N % 4 == 0, so r < N always here
        __syncthreads();
        xs[ty][tx] = x[r * DIM + tx];
        __syncthreads();
        float acc = 0.f;
#pragma unroll
        for (int k = 0; k < DIM; ++k) acc = fmaf(xs[ty][k], Ws[k][tx], acc);
        h[r * DIM + tx] = acc;
        float di = dinv[r];
        out[r * DIM + tx] = acc * di * di + bj;
    }
}

// one 64-lane group per edge, lane = output dim
__global__ __launch_bounds__(256) void k_scatter(const int* __restrict__ ei,
                                                 const float* __restrict__ h,
                                                 const float* __restrict__ dinv,
                                                 float* __restrict__ out, int E) {
    int t = blockIdx.x * blockDim.x + threadIdx.x;
    int e = t >> 6;
    int j = t & 63;
    if (e < E) {
        int s = ei[e];
        int d = ei[E + e];
        float nrm = dinv[s] * dinv[d];
        atomicAdd(&out[d * DIM + j], nrm * h[s * DIM + j]);
    }
}

// column-wise sum and sumsq -> stats[0..63] = sum, stats[64..127] = sumsq
__global__ __launch_bounds__(256) void k_stats(const float* __restrict__ out,
                                               float* __restrict__ stats, int N) {
    int tx = threadIdx.x & 63, ty = threadIdx.x >> 6;
    float s = 0.f, q = 0.f;
    for (int r = blockIdx.x * 4 + ty; r < N; r += gridDim.x * 4) {
        float v = out[r * DIM + tx];
        s += v;
        q = fmaf(v, v, q);
    }
    __shared__ float ls[4][DIM], lq[4][DIM];
    ls[ty][tx] = s;
    lq[ty][tx] = q;
    __syncthreads();
    if (ty == 0) {
        s = ls[0][tx] + ls[1][tx] + ls[2][tx] + ls[3][tx];
        q = lq[0][tx] + lq[1][tx] + lq[2][tx] + lq[3][tx];
        atomicAdd(&stats[tx], s);
        atomicAdd(&stats[DIM + tx], q);
    }
}

// BN(train, biased var) -> ReLU -> row L2 normalize ; in-place on out
__global__ __launch_bounds__(256) void k_final(float* __restrict__ out,
                                               const float* __restrict__ stats,
                                               const float* __restrict__ gamma,
                                               const float* __restrict__ beta,
                                               int N, float invN) {
    int tx = threadIdx.x & 63;
    int r = (blockIdx.x * blockDim.x + threadIdx.x) >> 6;
    if (r >= N) return;
    float mean = stats[tx] * invN;
    float var = fmaf(-mean, mean, stats[DIM + tx] * invN);
    float rstd = rsqrtf(var + BN_EPS);
    float v = out[r * DIM + tx];
    v = (v - mean) * rstd * gamma[tx] + beta[tx];
    v = fmaxf(v, 0.f);
    float q = v * v;
#pragma unroll
    for (int off = 32; off; off >>= 1) q += __shfl_xor(q, off, 64);
    float nrm = sqrtf(q);
    out[r * DIM + tx] = v / fmaxf(nrm, L2_EPS);
}

extern "C" void kernel_launch(void* const* d_in, const int* in_sizes, int n_in,
                              void* d_out, int out_size, void* d_ws, size_t ws_size,
                              hipStream_t stream) {
    const float* x     = (const float*)d_in[0];
    const int*   ei    = (const int*)d_in[1];
    const float* W     = (const float*)d_in[2];
    const float* b     = (const float*)d_in[3];
    const float* gamma = (const float*)d_in[4];
    const float* beta  = (const float*)d_in[5];
    float* out = (float*)d_out;

    const int N = in_sizes[0] / DIM;      // 50000
    const int E = in_sizes[1] / 2;        // 800000

    // workspace layout: [deg/dinv: N][h: N*DIM][stats: 128]
    float* deg   = (float*)d_ws;
    float* h     = deg + ((N + 255) & ~255);
    float* stats = h + (size_t)N * DIM;

    hipMemsetAsync(stats, 0, 2 * DIM * sizeof(float), stream);

    k_init_deg<<<(N + 255) / 256, 256, 0, stream>>>(deg, N);
    k_count_deg<<<(E + 255) / 256, 256, 0, stream>>>(ei, deg, E);
    k_rsqrt_deg<<<(N + 255) / 256, 256, 0, stream>>>(deg, N);
    k_gemm<<<2048, 256, 0, stream>>>(x, W, b, deg, h, out, N);
    k_scatter<<<(E * 64 + 255) / 256, 256, 0, stream>>>(ei, h, deg, out, E);
    k_stats<<<512, 256, 0, stream>>>(out, stats, N);
    k_final<<<(N * 64 + 255) / 256, 256, 0, stream>>>(out, stats, gamma, beta, N, 1.0f / N);
}